// Round 6
// baseline (474.161 us; speedup 1.0000x reference)
//
#include <hip/hip_runtime.h>
#include <hip/hip_bf16.h>

#define T 512
#define H 128
#define V 32000
#define B 2
#define CH 64   // RNN steps staged per LDS chunk

typedef __attribute__((ext_vector_type(8))) short bf16x8;
typedef __attribute__((ext_vector_type(4))) float f32x4;

__device__ __forceinline__ unsigned short f2bf(float f){
  unsigned int u = __float_as_uint(f);
  u = (u + 0x7FFFu + ((u >> 16) & 1u)) >> 16;
  return (unsigned short)u;
}

// tanh(x) = 1 - 2/(e^{2x}+1). e->inf gives 1, e->0 gives -1 (no clamp needed).
__device__ __forceinline__ float fast_tanh(float x){
  float e = __expf(2.f * x);
  return 1.f - __fdividef(2.f, e + 1.f);
}

// Quad (4-lane) sum via DPP quad_perm — VALU-only, ~4 cyc. __shfl_xor lowers to
// ds_swizzle_b32 (LDS pipe, ~100-120 cyc latency each, m117) and sat TWICE on the
// RNN step's serial critical path. quad_perm [1,0,3,2]=0xB1 (xor1), [2,3,0,1]=0x4E
// (xor2). After both stages every lane of the quad holds the full 4-lane sum.
__device__ __forceinline__ float quad_reduce_add(float x){
  int y1 = __builtin_amdgcn_mov_dpp(__float_as_int(x), 0xB1, 0xF, 0xF, true);
  float s1 = x + __int_as_float(y1);
  int y2 = __builtin_amdgcn_mov_dpp(__float_as_int(s1), 0x4E, 0xF, 0xF, true);
  return s1 + __int_as_float(y2);
}

// h-vector bank swizzle: h[k] (k = q*32 + 4n + j) lives at LDS word n*16 + q*4 + j.
// Reader thread (i,q) block n reads words n*16 + q*4 + j -> per instruction the 4
// distinct q-addresses cover 16 consecutive banks: conflict-free broadcast.
// (Round-5 verdict: conflicts 262K -> 6K, but only -4.4us: conflicts were hidden
// under the latency chain. Keep the swizzle — it's free — but the chain is the
// target now.)
__device__ __forceinline__ int hswz(int k){
  return ((k >> 2) & 7) * 16 + ((k >> 5) << 2) + (k & 3);
}

// async global->LDS, 16B per lane; lds base must be wave-uniform.
__device__ __forceinline__ void gload_lds16(const float* g, float* l){
  __builtin_amdgcn_global_load_lds((const __attribute__((address_space(1))) void*)g,
                                   (__attribute__((address_space(3))) void*)l, 16, 0, 0);
}

// ---------------- Kernel 1: prep = embedding/input-projection + Wfc->bf16 ----------------
__global__ __launch_bounds__(128) void prep_kernel(const int* __restrict__ x,
    const float* __restrict__ table, const float* __restrict__ W_ih,
    const float* __restrict__ b_ih, const float* __restrict__ b_hh,
    const float* __restrict__ Wfc,
    float* __restrict__ xp, unsigned short* __restrict__ wfcb){
  int blk = blockIdx.x;
  int tid = threadIdx.x;
  __shared__ __align__(16) float e[32];
  if (blk < B * T){
    if (tid < 32) e[tid] = table[(size_t)x[blk] * 32 + tid];
    __syncthreads();
    const float* wr = W_ih + tid * 32;
    float a0 = 0.f, a1 = 0.f, a2 = 0.f, a3 = 0.f;
    #pragma unroll
    for (int k = 0; k < 32; k += 4){
      float4 w4 = *(const float4*)(wr + k);
      float4 e4 = *(const float4*)(e + k);
      a0 += w4.x * e4.x; a1 += w4.y * e4.y; a2 += w4.z * e4.z; a3 += w4.w * e4.w;
    }
    xp[(size_t)blk * H + tid] = (a0 + a1) + (a2 + a3) + b_ih[tid] + b_hh[tid];
  } else {
    size_t base = (size_t)(blk - B * T) * 1024 + (size_t)tid * 8;
    float4 f0 = *(const float4*)(Wfc + base);
    float4 f1 = *(const float4*)(Wfc + base + 4);
    ushort4 o0, o1;
    o0.x = f2bf(f0.x); o0.y = f2bf(f0.y); o0.z = f2bf(f0.z); o0.w = f2bf(f0.w);
    o1.x = f2bf(f1.x); o1.y = f2bf(f1.y); o1.z = f2bf(f1.z); o1.w = f2bf(f1.w);
    *(ushort4*)(wfcb + base) = o0;
    *(ushort4*)(wfcb + base + 4) = o1;
  }
}

// ---------------- Kernel 2: serial RNN scan, one block per batch chain ----------------
// 512 threads (2 waves/SIMD; round-3 proved 1 wave/SIMD loses latency hiding).
// thread -> output i = tid>>2, k-quarter q = tid&3; 32 weight VGPRs pinned via asm.
// ROUND-6: quad_reduce_add (DPP) replaces the two __shfl_xor (ds_swizzle, 2x ~110
// cyc LDS-pipe latency) on the step's serial chain; h-writes split across q=0/q=1
// lanes (all quad lanes hold hn after the DPP reduce).
// Steady-state step loop has ZERO global memory ops: xp staged via global_load_lds
// in double-buffered 64-step chunks; h history flushed per chunk, coalesced.
__global__ __launch_bounds__(512, 1) void rnn_kernel(const float* __restrict__ xp,
    const float* __restrict__ hidden, const float* __restrict__ W_hh,
    float* __restrict__ rnn, float* __restrict__ hid_out){
  int b = blockIdx.x;
  int tid = threadIdx.x;
  int i = tid >> 2, q = tid & 3;
  int wv = tid >> 6;                 // wave id (uniform within wave)
  const float* wrow = W_hh + (size_t)i * H + q * 32;
  f32x4 W0 = *(const f32x4*)(wrow);
  f32x4 W1 = *(const f32x4*)(wrow + 4);
  f32x4 W2 = *(const f32x4*)(wrow + 8);
  f32x4 W3 = *(const f32x4*)(wrow + 12);
  f32x4 W4 = *(const f32x4*)(wrow + 16);
  f32x4 W5 = *(const f32x4*)(wrow + 20);
  f32x4 W6 = *(const f32x4*)(wrow + 24);
  f32x4 W7 = *(const f32x4*)(wrow + 28);
  asm volatile("" : "+v"(W0), "+v"(W1), "+v"(W2), "+v"(W3),
                    "+v"(W4), "+v"(W5), "+v"(W6), "+v"(W7));

  __shared__ __align__(16) float xs[2][CH][H];   // 64 KB: xp chunk double-buffer
  __shared__ __align__(16) float hist[CH][H];    // 32 KB: h history (linear layout)
  __shared__ __align__(16) float hb[2][H];       // ping-pong h state (hswz layout)

  const float* xpb = xp + (size_t)b * T * H;

  // prologue: async-load chunk 0 (64 lanes x 16B per wave-issue; 4 issues/thread)
  #pragma unroll
  for (int is = 0; is < 4; ++is)
    gload_lds16(xpb + is * 2048 + tid * 4, &xs[0][0][0] + wv * 256 + is * 2048);
  if (tid < H) hb[0][hswz(tid)] = hidden[b * H + tid];
  __syncthreads();   // drains chunk-0 load + hidden load

  // swizzled write position for this thread's output row
  int wpos = hswz(i);
  float hn = 0.f;
  int cur = 0, buf = 0;
  for (int chunk = 0; chunk < T / CH; ++chunk){
    // issue next chunk's loads now; they drain at this chunk's FIRST inner barrier
    // (one latency hit amortized over CH steps). Writers target xs[buf^1], which
    // no thread reads until after that barrier.
    if (chunk + 1 < T / CH){
      const float* src = xpb + (size_t)(chunk + 1) * CH * H;
      #pragma unroll
      for (int is = 0; is < 4; ++is)
        gload_lds16(src + is * 2048 + tid * 4, &xs[buf ^ 1][0][0] + wv * 256 + is * 2048);
    }
    for (int s = 0; s < CH; ++s){
      float xv = xs[buf][s][i];          // LDS broadcast (4 lanes share address)
      const float* hs = &hb[cur][q * 4]; // swizzled base; block n at +16*n
      float a0 = 0.f, a1 = 0.f, a2 = 0.f, a3 = 0.f;
#define FMA4(n) { f32x4 hv = *(const f32x4*)(hs + 16 * n); \
    a0 = fmaf(hv.x, W##n.x, a0); a1 = fmaf(hv.y, W##n.y, a1); \
    a2 = fmaf(hv.z, W##n.z, a2); a3 = fmaf(hv.w, W##n.w, a3); }
      FMA4(0) FMA4(1) FMA4(2) FMA4(3) FMA4(4) FMA4(5) FMA4(6) FMA4(7)
#undef FMA4
      float sum = quad_reduce_add((a0 + a1) + (a2 + a3));
      hn = fast_tanh(xv + sum);
      if (q == 0) hb[cur ^ 1][wpos] = hn;   // next-step state (swizzled)
      if (q == 1) hist[s][i] = hn;          // history (linear) — parallel lane
      __syncthreads();                   // steady state: lgkm-only drain (no vmem)
      cur ^= 1;
    }
    // flush h history: flat LDS->reg->global, 64B/thread, wave writes 1KB contiguous
    {
      const float* hsrc = &hist[0][0] + tid * 16;
      float* dst = rnn + (size_t)b * T * H + (size_t)chunk * CH * H + tid * 16;
      float4 f0 = *(const float4*)(hsrc);
      float4 f1 = *(const float4*)(hsrc + 4);
      float4 f2 = *(const float4*)(hsrc + 8);
      float4 f3 = *(const float4*)(hsrc + 12);
      *(float4*)(dst)      = f0;
      *(float4*)(dst + 4)  = f1;
      *(float4*)(dst + 8)  = f2;
      *(float4*)(dst + 12) = f3;
    }
    buf ^= 1;
    __syncthreads();   // flush LDS reads complete before hist reuse next chunk
  }
  if (q == 0) hid_out[b * H + i] = hn;
}

// ---------------- Kernel 3: query/key projections ----------------
__global__ __launch_bounds__(256) void qk_kernel(const float* __restrict__ rnn,
    const float* __restrict__ W1, const float* __restrict__ W2,
    float* __restrict__ q, float* __restrict__ ky){
  int bt = blockIdx.x;
  int tid = threadIdx.x;
  __shared__ __align__(16) float r[H];
  if (tid < H) r[tid] = rnn[(size_t)bt * H + tid];
  __syncthreads();
  int i = tid & (H - 1);
  const float* wrow = ((tid < H) ? W1 : W2) + (size_t)i * H;
  float a0 = 0.f, a1 = 0.f, a2 = 0.f, a3 = 0.f;
  #pragma unroll 8
  for (int k = 0; k < H; k += 4){
    float4 w4 = *(const float4*)(wrow + k);
    float4 r4 = *(const float4*)(r + k);
    a0 += w4.x * r4.x; a1 += w4.y * r4.y; a2 += w4.z * r4.z; a3 += w4.w * r4.w;
  }
  float res = (a0 + a1) + (a2 + a3);
  if (tid < H) q[(size_t)bt * H + i] = res;
  else         ky[(size_t)bt * H + i] = res;
}

// ---------------- Kernel 4: attention scores + softmax + context + Wp/relu ----------------
__global__ __launch_bounds__(256) void attn_kernel(const float* __restrict__ rnn,
    const float* __restrict__ q, const float* __restrict__ ky,
    const float* __restrict__ v, const float* __restrict__ Wp,
    const float* __restrict__ bp, float* __restrict__ wout,
    unsigned short* __restrict__ outb){
  int bt = blockIdx.x;
  int b = bt >> 9, t = bt & (T - 1);
  int tid = threadIdx.x;
  __shared__ __align__(16) float qL[H], vL[H], rrL[H], ctxL[H];
  __shared__ __align__(16) float ctx2[2][H];
  __shared__ __align__(16) float scL[T], wL[T];
  __shared__ float red[4], red2[4];
  if (tid < H){
    qL[tid]  = q[(size_t)bt * H + tid];
    vL[tid]  = v[tid];
    rrL[tid] = rnn[(size_t)bt * H + tid];
  }
  __syncthreads();
  for (int s = tid; s < T; s += 256){
    float sc = -1e30f;
    if (s <= t){
      const float* kr = ky + (size_t)(b * T + s) * H;
      float a0 = 0.f, a1 = 0.f, a2 = 0.f, a3 = 0.f;
      #pragma unroll 4
      for (int h = 0; h < H; h += 4){
        float4 kv = *(const float4*)(kr + h);
        float4 qv = *(const float4*)(qL + h);
        float4 vv = *(const float4*)(vL + h);
        a0 += fast_tanh(qv.x + kv.x) * vv.x;
        a1 += fast_tanh(qv.y + kv.y) * vv.y;
        a2 += fast_tanh(qv.z + kv.z) * vv.z;
        a3 += fast_tanh(qv.w + kv.w) * vv.w;
      }
      sc = (a0 + a1) + (a2 + a3);
    }
    scL[s] = sc;
  }
  __syncthreads();
  float m = -1e30f;
  for (int s = tid; s < T; s += 256) m = fmaxf(m, scL[s]);
  #pragma unroll
  for (int o = 32; o > 0; o >>= 1) m = fmaxf(m, __shfl_xor(m, o));
  if ((tid & 63) == 0) red[tid >> 6] = m;
  __syncthreads();
  float mx = fmaxf(fmaxf(red[0], red[1]), fmaxf(red[2], red[3]));
  float ls = 0.f;
  for (int s = tid; s < T; s += 256){
    float e = (s <= t) ? __expf(scL[s] - mx) : 0.f;
    wL[s] = e; ls += e;
  }
  #pragma unroll
  for (int o = 32; o > 0; o >>= 1) ls += __shfl_xor(ls, o);
  if ((tid & 63) == 0) red2[tid >> 6] = ls;
  __syncthreads();
  float inv = 1.f / (red2[0] + red2[1] + red2[2] + red2[3]);
  for (int s = tid; s < T; s += 256){
    float wv = wL[s] * inv;
    wL[s] = wv;
    wout[(size_t)bt * T + s] = wv;
  }
  __syncthreads();
  // context: all 256 threads. thread -> dim i2 = tid&127, s-parity hf = tid>>7.
  {
    int i2 = tid & (H - 1), hf = tid >> 7;
    const float* rb = rnn + (size_t)b * T * H + i2;
    float c0 = 0.f, c1 = 0.f, c2 = 0.f, c3 = 0.f;
    int s = hf;
    for (; s + 6 <= t; s += 8){
      c0 += wL[s]     * rb[(size_t)s * H];
      c1 += wL[s + 2] * rb[(size_t)(s + 2) * H];
      c2 += wL[s + 4] * rb[(size_t)(s + 4) * H];
      c3 += wL[s + 6] * rb[(size_t)(s + 6) * H];
    }
    for (; s <= t; s += 2) c0 += wL[s] * rb[(size_t)s * H];
    ctx2[hf][i2] = (c0 + c1) + (c2 + c3);
  }
  __syncthreads();
  if (tid < H) ctxL[tid] = ctx2[0][tid] + ctx2[1][tid];
  __syncthreads();
  if (tid < H){
    const float* wp = Wp + (size_t)tid * (2 * H);
    float a0 = 0.f, a1 = 0.f, a2 = 0.f, a3 = 0.f;
    #pragma unroll 8
    for (int k = 0; k < H; k += 4){
      float4 w4 = *(const float4*)(wp + k);
      float4 r4 = *(const float4*)(rrL + k);
      a0 += w4.x * r4.x; a1 += w4.y * r4.y; a2 += w4.z * r4.z; a3 += w4.w * r4.w;
    }
    #pragma unroll 8
    for (int k = 0; k < H; k += 4){
      float4 w4 = *(const float4*)(wp + H + k);
      float4 c4 = *(const float4*)(ctxL + k);
      a0 += w4.x * c4.x; a1 += w4.y * c4.y; a2 += w4.z * c4.z; a3 += w4.w * c4.w;
    }
    float o = bp[tid] + (a0 + a1) + (a2 + a3);
    o = fmaxf(o, 0.f);
    outb[(size_t)bt * H + tid] = f2bf(o);
  }
}

// ---------------- Kernel 5: logits = out @ Wfc.T + bfc  (bf16 MFMA) ----------------
__global__ __launch_bounds__(256, 1) void gemm_kernel(const unsigned short* __restrict__ Ab,
    const unsigned short* __restrict__ Bb, const float* __restrict__ bfc,
    float* __restrict__ Cout){
  int tid = threadIdx.x;
  int l = tid & 63, wv = tid >> 6;
  int lm = l & 15, lq = l >> 4;
  int nBase = blockIdx.x * 128;
  bf16x8 bw[32];
  const unsigned short* bp = Bb + (size_t)(nBase + lm) * H + lq * 8;
  #pragma unroll
  for (int sub = 0; sub < 8; ++sub)
    #pragma unroll
    for (int kk = 0; kk < 4; ++kk)
      bw[sub * 4 + kk] = *(const bf16x8*)(bp + (size_t)sub * 16 * H + kk * 32);
  float bias[8];
  #pragma unroll
  for (int sub = 0; sub < 8; ++sub) bias[sub] = bfc[nBase + lm + sub * 16];
  #pragma unroll 1
  for (int mb = 0; mb < 16; ++mb){
    int rowA = mb * 64 + wv * 16 + lm;
    const unsigned short* ap = Ab + (size_t)rowA * H + lq * 8;
    bf16x8 af[4];
    #pragma unroll
    for (int kk = 0; kk < 4; ++kk) af[kk] = *(const bf16x8*)(ap + kk * 32);
    f32x4 acc[8];
    #pragma unroll
    for (int s = 0; s < 8; ++s) acc[s] = (f32x4){0.f, 0.f, 0.f, 0.f};
    #pragma unroll
    for (int kk = 0; kk < 4; ++kk)
      #pragma unroll
      for (int sub = 0; sub < 8; ++sub)
        acc[sub] = __builtin_amdgcn_mfma_f32_16x16x32_bf16(af[kk], bw[sub * 4 + kk], acc[sub], 0, 0, 0);
    int row0 = mb * 64 + wv * 16 + lq * 4;
    #pragma unroll
    for (int sub = 0; sub < 8; ++sub){
      int c = nBase + lm + sub * 16;
      #pragma unroll
      for (int r = 0; r < 4; ++r)
        Cout[(size_t)(row0 + r) * V + c] = acc[sub][r] + bias[sub];
    }
  }
}

extern "C" void kernel_launch(void* const* d_in, const int* in_sizes, int n_in,
                              void* d_out, int out_size, void* d_ws, size_t ws_size,
                              hipStream_t stream){
  const int*   x      = (const int*)d_in[0];
  const float* hidden = (const float*)d_in[1];
  const float* table  = (const float*)d_in[2];
  const float* W_ih   = (const float*)d_in[3];
  const float* W_hh   = (const float*)d_in[4];
  const float* b_ih   = (const float*)d_in[5];
  const float* b_hh   = (const float*)d_in[6];
  const float* W1     = (const float*)d_in[7];
  const float* W2     = (const float*)d_in[8];
  const float* v      = (const float*)d_in[9];
  const float* Wp     = (const float*)d_in[10];
  const float* bp     = (const float*)d_in[11];
  const float* Wfc    = (const float*)d_in[12];
  const float* bfc    = (const float*)d_in[13];

  float* out     = (float*)d_out;
  float* logits  = out;                              // (B,T,V)
  float* hid_out = out + (size_t)B * T * V;          // (1,B,H)
  float* w_out   = hid_out + (size_t)B * H;          // (B,T,T)

  float* xp  = (float*)d_ws;
  float* rnn = xp  + (size_t)B * T * H;
  float* q   = rnn + (size_t)B * T * H;
  float* ky  = q   + (size_t)B * T * H;
  unsigned short* outb = (unsigned short*)(ky + (size_t)B * T * H);
  unsigned short* wfcb = outb + (size_t)B * T * H;

  prep_kernel<<<B * T + (V * H) / 1024, 128, 0, stream>>>(x, table, W_ih, b_ih, b_hh, Wfc, xp, wfcb);
  rnn_kernel<<<B, 512, 0, stream>>>(xp, hidden, W_hh, rnn, hid_out);
  qk_kernel<<<B * T, 256, 0, stream>>>(rnn, W1, W2, q, ky);
  attn_kernel<<<B * T, 256, 0, stream>>>(rnn, q, ky, v, Wp, bp, w_out, outb);
  gemm_kernel<<<V / 128, 256, 0, stream>>>(outb, wfcb, bfc, logits);
}

// Round 7
// 448.523 us; speedup vs baseline: 1.0572x; 1.0572x over previous
//
#include <hip/hip_runtime.h>
#include <hip/hip_bf16.h>

#define T 512
#define H 128
#define V 32000
#define B 2
#define CH 64   // RNN steps staged per LDS chunk

typedef __attribute__((ext_vector_type(8))) short bf16x8;
typedef __attribute__((ext_vector_type(4))) float f32x4;

__device__ __forceinline__ unsigned short f2bf(float f){
  unsigned int u = __float_as_uint(f);
  u = (u + 0x7FFFu + ((u >> 16) & 1u)) >> 16;
  return (unsigned short)u;
}

// tanh(x) = 1 - 2/(e^{2x}+1). e->inf gives 1, e->0 gives -1 (no clamp needed).
__device__ __forceinline__ float fast_tanh(float x){
  float e = __expf(2.f * x);
  return 1.f - __fdividef(2.f, e + 1.f);
}

// Quad (4-lane) sum via DPP quad_perm — VALU-only. (Round-6: neutral vs shfl_xor,
// kept because it's not worse and frees the LDS pipe, which IS the bottleneck.)
__device__ __forceinline__ float quad_reduce_add(float x){
  int y1 = __builtin_amdgcn_mov_dpp(__float_as_int(x), 0xB1, 0xF, 0xF, true);
  float s1 = x + __int_as_float(y1);
  int y2 = __builtin_amdgcn_mov_dpp(__float_as_int(s1), 0x4E, 0xF, 0xF, true);
  return s1 + __int_as_float(y2);
}

// h-vector bank swizzle: h[k] (k = q*32 + 4n + j) lives at LDS word n*16 + q*4 + j.
// Per ds_read_b128 the 4 distinct q-addresses cover 16 consecutive banks ->
// conflict-free (verified r5: 262K -> 6K SQ_LDS_BANK_CONFLICT).
__device__ __forceinline__ int hswz(int k){
  return ((k >> 2) & 7) * 16 + ((k >> 5) << 2) + (k & 3);
}

// async global->LDS, 16B per lane; lds base must be wave-uniform.
__device__ __forceinline__ void gload_lds16(const float* g, float* l){
  __builtin_amdgcn_global_load_lds((const __attribute__((address_space(1))) void*)g,
                                   (__attribute__((address_space(3))) void*)l, 16, 0, 0);
}

// ---------------- Kernel 1: prep = embedding/input-projection + Wfc->bf16 ----------------
__global__ __launch_bounds__(128) void prep_kernel(const int* __restrict__ x,
    const float* __restrict__ table, const float* __restrict__ W_ih,
    const float* __restrict__ b_ih, const float* __restrict__ b_hh,
    const float* __restrict__ Wfc,
    float* __restrict__ xp, unsigned short* __restrict__ wfcb){
  int blk = blockIdx.x;
  int tid = threadIdx.x;
  __shared__ __align__(16) float e[32];
  if (blk < B * T){
    if (tid < 32) e[tid] = table[(size_t)x[blk] * 32 + tid];
    __syncthreads();
    const float* wr = W_ih + tid * 32;
    float a0 = 0.f, a1 = 0.f, a2 = 0.f, a3 = 0.f;
    #pragma unroll
    for (int k = 0; k < 32; k += 4){
      float4 w4 = *(const float4*)(wr + k);
      float4 e4 = *(const float4*)(e + k);
      a0 += w4.x * e4.x; a1 += w4.y * e4.y; a2 += w4.z * e4.z; a3 += w4.w * e4.w;
    }
    xp[(size_t)blk * H + tid] = (a0 + a1) + (a2 + a3) + b_ih[tid] + b_hh[tid];
  } else {
    size_t base = (size_t)(blk - B * T) * 1024 + (size_t)tid * 8;
    float4 f0 = *(const float4*)(Wfc + base);
    float4 f1 = *(const float4*)(Wfc + base + 4);
    ushort4 o0, o1;
    o0.x = f2bf(f0.x); o0.y = f2bf(f0.y); o0.z = f2bf(f0.z); o0.w = f2bf(f0.w);
    o1.x = f2bf(f1.x); o1.y = f2bf(f1.y); o1.z = f2bf(f1.z); o1.w = f2bf(f1.w);
    *(ushort4*)(wfcb + base) = o0;
    *(ushort4*)(wfcb + base + 4) = o1;
  }
}

// ---------------- Kernel 2: serial RNN scan, one block per batch chain ----------------
// ROUND-7 RESHAPE (model from r5/r6 nulls: step cost = DS-instr issue burst + barrier,
// NOT conflicts/shfl/global): 256 threads, lane -> rows {2qp, 2qp+1} (qp=tid>>2),
// k-slice q=tid&3. Each h fragment read now feeds 8 FMAs (2 rows) instead of 4 ->
// DS reads 64 -> 32 instrs/step; total DS ~44/step (was 88); barrier width 8 -> 4
// waves. FMA issue 64/lane x 2cyc = 128 cyc (1 wave/SIMD, all 4 SIMDs) stays below
// the DS term. 128 weight VGPRs/lane pinned via asm (2x16-operand statements).
// Steady-state step loop has ZERO global memory ops (xp staged via global_load_lds,
// h history flushed per chunk).
__global__ __launch_bounds__(256, 1) void rnn_kernel(const float* __restrict__ xp,
    const float* __restrict__ hidden, const float* __restrict__ W_hh,
    float* __restrict__ rnn, float* __restrict__ hid_out){
  int b = blockIdx.x;
  int tid = threadIdx.x;
  int qp = tid >> 2, q = tid & 3;
  int wv = tid >> 6;                 // wave id (uniform within wave)
  int r0 = 2 * qp;
  const float* wra = W_hh + (size_t)r0 * H + q * 32;   // row r0, slice q
  const float* wrb = wra + H;                          // row r0+1, slice q
  f32x4 A0 = *(const f32x4*)(wra);
  f32x4 A1 = *(const f32x4*)(wra + 4);
  f32x4 A2 = *(const f32x4*)(wra + 8);
  f32x4 A3 = *(const f32x4*)(wra + 12);
  f32x4 A4 = *(const f32x4*)(wra + 16);
  f32x4 A5 = *(const f32x4*)(wra + 20);
  f32x4 A6 = *(const f32x4*)(wra + 24);
  f32x4 A7 = *(const f32x4*)(wra + 28);
  f32x4 B0 = *(const f32x4*)(wrb);
  f32x4 B1 = *(const f32x4*)(wrb + 4);
  f32x4 B2 = *(const f32x4*)(wrb + 8);
  f32x4 B3 = *(const f32x4*)(wrb + 12);
  f32x4 B4 = *(const f32x4*)(wrb + 16);
  f32x4 B5 = *(const f32x4*)(wrb + 20);
  f32x4 B6 = *(const f32x4*)(wrb + 24);
  f32x4 B7 = *(const f32x4*)(wrb + 28);
  // pin weights in registers (RA cannot rematerialize an asm result)
  asm volatile("" : "+v"(A0), "+v"(A1), "+v"(A2), "+v"(A3),
                    "+v"(A4), "+v"(A5), "+v"(A6), "+v"(A7));
  asm volatile("" : "+v"(B0), "+v"(B1), "+v"(B2), "+v"(B3),
                    "+v"(B4), "+v"(B5), "+v"(B6), "+v"(B7));

  __shared__ __align__(16) float xs[2][CH][H];   // 64 KB: xp chunk double-buffer
  __shared__ __align__(16) float hist[CH][H];    // 32 KB: h history (linear layout)
  __shared__ __align__(16) float hb[2][H];       // ping-pong h state (hswz layout)

  const float* xpb = xp + (size_t)b * T * H;

  // prologue: async-load chunk 0 (8 issue rounds x 256 lanes x 16B = 32 KB)
  #pragma unroll
  for (int is = 0; is < 8; ++is)
    gload_lds16(xpb + is * 1024 + tid * 4, &xs[0][0][0] + is * 1024 + wv * 256);
  if (tid < H) hb[0][hswz(tid)] = hidden[b * H + tid];
  __syncthreads();   // drains chunk-0 load + hidden load

  // swizzled write position: rows r0,r0+1 land on adjacent words (r0&3 in {0,2})
  int wpos = hswz(r0);
  float hn0 = 0.f, hn1 = 0.f;
  int cur = 0, buf = 0;
  for (int chunk = 0; chunk < T / CH; ++chunk){
    // issue next chunk's loads now; they drain at this chunk's FIRST inner barrier
    if (chunk + 1 < T / CH){
      const float* src = xpb + (size_t)(chunk + 1) * CH * H;
      #pragma unroll
      for (int is = 0; is < 8; ++is)
        gload_lds16(src + is * 1024 + tid * 4, &xs[buf ^ 1][0][0] + is * 1024 + wv * 256);
    }
    for (int s = 0; s < CH; ++s){
      float2 xv = *(const float2*)(&xs[buf][s][r0]);  // ds_read_b64 (4-lane bcast)
      const float* hs = &hb[cur][q * 4];              // swizzled base; block n at +16n
      float a0 = 0.f, a1 = 0.f, b0 = 0.f, b1 = 0.f;
#define FMA8(n) { f32x4 hv = *(const f32x4*)(hs + 16 * n); \
    a0 = fmaf(hv.x, A##n.x, a0); a1 = fmaf(hv.y, A##n.y, a1); \
    a0 = fmaf(hv.z, A##n.z, a0); a1 = fmaf(hv.w, A##n.w, a1); \
    b0 = fmaf(hv.x, B##n.x, b0); b1 = fmaf(hv.y, B##n.y, b1); \
    b0 = fmaf(hv.z, B##n.z, b0); b1 = fmaf(hv.w, B##n.w, b1); }
      FMA8(0) FMA8(1) FMA8(2) FMA8(3) FMA8(4) FMA8(5) FMA8(6) FMA8(7)
#undef FMA8
      float sa = quad_reduce_add(a0 + a1);
      float sb = quad_reduce_add(b0 + b1);
      hn0 = fast_tanh(xv.x + sa);
      hn1 = fast_tanh(xv.y + sb);
      if (q == 0){                       // next-step state (swizzled, adjacent words)
        float2 hw; hw.x = hn0; hw.y = hn1;
        *(float2*)(&hb[cur ^ 1][wpos]) = hw;
      }
      if (q == 1){                       // history (linear) — parallel lane
        float2 hw; hw.x = hn0; hw.y = hn1;
        *(float2*)(&hist[s][r0]) = hw;
      }
      __syncthreads();                   // steady state: lgkm-only drain (no vmem)
      cur ^= 1;
    }
    // flush h history: 8 rounds, each 256 threads x float4 = 4 KB contiguous
    {
      const float* hsrc = &hist[0][0];
      float* dst = rnn + (size_t)b * T * H + (size_t)chunk * CH * H;
      #pragma unroll
      for (int r = 0; r < 8; ++r)
        *(float4*)(dst + r * 1024 + tid * 4) = *(const float4*)(hsrc + r * 1024 + tid * 4);
    }
    buf ^= 1;
    __syncthreads();   // flush LDS reads complete before hist reuse next chunk
  }
  if (q == 0){
    float2 hw; hw.x = hn0; hw.y = hn1;
    *(float2*)(&hid_out[b * H + r0]) = hw;
  }
}

// ---------------- Kernel 3: query/key projections ----------------
__global__ __launch_bounds__(256) void qk_kernel(const float* __restrict__ rnn,
    const float* __restrict__ W1, const float* __restrict__ W2,
    float* __restrict__ q, float* __restrict__ ky){
  int bt = blockIdx.x;
  int tid = threadIdx.x;
  __shared__ __align__(16) float r[H];
  if (tid < H) r[tid] = rnn[(size_t)bt * H + tid];
  __syncthreads();
  int i = tid & (H - 1);
  const float* wrow = ((tid < H) ? W1 : W2) + (size_t)i * H;
  float a0 = 0.f, a1 = 0.f, a2 = 0.f, a3 = 0.f;
  #pragma unroll 8
  for (int k = 0; k < H; k += 4){
    float4 w4 = *(const float4*)(wrow + k);
    float4 r4 = *(const float4*)(r + k);
    a0 += w4.x * r4.x; a1 += w4.y * r4.y; a2 += w4.z * r4.z; a3 += w4.w * r4.w;
  }
  float res = (a0 + a1) + (a2 + a3);
  if (tid < H) q[(size_t)bt * H + i] = res;
  else         ky[(size_t)bt * H + i] = res;
}

// ---------------- Kernel 4: attention scores + softmax + context + Wp/relu ----------------
__global__ __launch_bounds__(256) void attn_kernel(const float* __restrict__ rnn,
    const float* __restrict__ q, const float* __restrict__ ky,
    const float* __restrict__ v, const float* __restrict__ Wp,
    const float* __restrict__ bp, float* __restrict__ wout,
    unsigned short* __restrict__ outb){
  int bt = blockIdx.x;
  int b = bt >> 9, t = bt & (T - 1);
  int tid = threadIdx.x;
  __shared__ __align__(16) float qL[H], vL[H], rrL[H], ctxL[H];
  __shared__ __align__(16) float ctx2[2][H];
  __shared__ __align__(16) float scL[T], wL[T];
  __shared__ float red[4], red2[4];
  if (tid < H){
    qL[tid]  = q[(size_t)bt * H + tid];
    vL[tid]  = v[tid];
    rrL[tid] = rnn[(size_t)bt * H + tid];
  }
  __syncthreads();
  for (int s = tid; s < T; s += 256){
    float sc = -1e30f;
    if (s <= t){
      const float* kr = ky + (size_t)(b * T + s) * H;
      float a0 = 0.f, a1 = 0.f, a2 = 0.f, a3 = 0.f;
      #pragma unroll 4
      for (int h = 0; h < H; h += 4){
        float4 kv = *(const float4*)(kr + h);
        float4 qv = *(const float4*)(qL + h);
        float4 vv = *(const float4*)(vL + h);
        a0 += fast_tanh(qv.x + kv.x) * vv.x;
        a1 += fast_tanh(qv.y + kv.y) * vv.y;
        a2 += fast_tanh(qv.z + kv.z) * vv.z;
        a3 += fast_tanh(qv.w + kv.w) * vv.w;
      }
      sc = (a0 + a1) + (a2 + a3);
    }
    scL[s] = sc;
  }
  __syncthreads();
  float m = -1e30f;
  for (int s = tid; s < T; s += 256) m = fmaxf(m, scL[s]);
  #pragma unroll
  for (int o = 32; o > 0; o >>= 1) m = fmaxf(m, __shfl_xor(m, o));
  if ((tid & 63) == 0) red[tid >> 6] = m;
  __syncthreads();
  float mx = fmaxf(fmaxf(red[0], red[1]), fmaxf(red[2], red[3]));
  float ls = 0.f;
  for (int s = tid; s < T; s += 256){
    float e = (s <= t) ? __expf(scL[s] - mx) : 0.f;
    wL[s] = e; ls += e;
  }
  #pragma unroll
  for (int o = 32; o > 0; o >>= 1) ls += __shfl_xor(ls, o);
  if ((tid & 63) == 0) red2[tid >> 6] = ls;
  __syncthreads();
  float inv = 1.f / (red2[0] + red2[1] + red2[2] + red2[3]);
  for (int s = tid; s < T; s += 256){
    float wv = wL[s] * inv;
    wL[s] = wv;
    wout[(size_t)bt * T + s] = wv;
  }
  __syncthreads();
  // context: all 256 threads. thread -> dim i2 = tid&127, s-parity hf = tid>>7.
  {
    int i2 = tid & (H - 1), hf = tid >> 7;
    const float* rb = rnn + (size_t)b * T * H + i2;
    float c0 = 0.f, c1 = 0.f, c2 = 0.f, c3 = 0.f;
    int s = hf;
    for (; s + 6 <= t; s += 8){
      c0 += wL[s]     * rb[(size_t)s * H];
      c1 += wL[s + 2] * rb[(size_t)(s + 2) * H];
      c2 += wL[s + 4] * rb[(size_t)(s + 4) * H];
      c3 += wL[s + 6] * rb[(size_t)(s + 6) * H];
    }
    for (; s <= t; s += 2) c0 += wL[s] * rb[(size_t)s * H];
    ctx2[hf][i2] = (c0 + c1) + (c2 + c3);
  }
  __syncthreads();
  if (tid < H) ctxL[tid] = ctx2[0][tid] + ctx2[1][tid];
  __syncthreads();
  if (tid < H){
    const float* wp = Wp + (size_t)tid * (2 * H);
    float a0 = 0.f, a1 = 0.f, a2 = 0.f, a3 = 0.f;
    #pragma unroll 8
    for (int k = 0; k < H; k += 4){
      float4 w4 = *(const float4*)(wp + k);
      float4 r4 = *(const float4*)(rrL + k);
      a0 += w4.x * r4.x; a1 += w4.y * r4.y; a2 += w4.z * r4.z; a3 += w4.w * r4.w;
    }
    #pragma unroll 8
    for (int k = 0; k < H; k += 4){
      float4 w4 = *(const float4*)(wp + H + k);
      float4 c4 = *(const float4*)(ctxL + k);
      a0 += w4.x * c4.x; a1 += w4.y * c4.y; a2 += w4.z * c4.z; a3 += w4.w * c4.w;
    }
    float o = bp[tid] + (a0 + a1) + (a2 + a3);
    o = fmaxf(o, 0.f);
    outb[(size_t)bt * H + tid] = f2bf(o);
  }
}

// ---------------- Kernel 5: logits = out @ Wfc.T + bfc  (bf16 MFMA) ----------------
__global__ __launch_bounds__(256, 1) void gemm_kernel(const unsigned short* __restrict__ Ab,
    const unsigned short* __restrict__ Bb, const float* __restrict__ bfc,
    float* __restrict__ Cout){
  int tid = threadIdx.x;
  int l = tid & 63, wv = tid >> 6;
  int lm = l & 15, lq = l >> 4;
  int nBase = blockIdx.x * 128;
  bf16x8 bw[32];
  const unsigned short* bp = Bb + (size_t)(nBase + lm) * H + lq * 8;
  #pragma unroll
  for (int sub = 0; sub < 8; ++sub)
    #pragma unroll
    for (int kk = 0; kk < 4; ++kk)
      bw[sub * 4 + kk] = *(const bf16x8*)(bp + (size_t)sub * 16 * H + kk * 32);
  float bias[8];
  #pragma unroll
  for (int sub = 0; sub < 8; ++sub) bias[sub] = bfc[nBase + lm + sub * 16];
  #pragma unroll 1
  for (int mb = 0; mb < 16; ++mb){
    int rowA = mb * 64 + wv * 16 + lm;
    const unsigned short* ap = Ab + (size_t)rowA * H + lq * 8;
    bf16x8 af[4];
    #pragma unroll
    for (int kk = 0; kk < 4; ++kk) af[kk] = *(const bf16x8*)(ap + kk * 32);
    f32x4 acc[8];
    #pragma unroll
    for (int s = 0; s < 8; ++s) acc[s] = (f32x4){0.f, 0.f, 0.f, 0.f};
    #pragma unroll
    for (int kk = 0; kk < 4; ++kk)
      #pragma unroll
      for (int sub = 0; sub < 8; ++sub)
        acc[sub] = __builtin_amdgcn_mfma_f32_16x16x32_bf16(af[kk], bw[sub * 4 + kk], acc[sub], 0, 0, 0);
    int row0 = mb * 64 + wv * 16 + lq * 4;
    #pragma unroll
    for (int sub = 0; sub < 8; ++sub){
      int c = nBase + lm + sub * 16;
      #pragma unroll
      for (int r = 0; r < 4; ++r)
        Cout[(size_t)(row0 + r) * V + c] = acc[sub][r] + bias[sub];
    }
  }
}

extern "C" void kernel_launch(void* const* d_in, const int* in_sizes, int n_in,
                              void* d_out, int out_size, void* d_ws, size_t ws_size,
                              hipStream_t stream){
  const int*   x      = (const int*)d_in[0];
  const float* hidden = (const float*)d_in[1];
  const float* table  = (const float*)d_in[2];
  const float* W_ih   = (const float*)d_in[3];
  const float* W_hh   = (const float*)d_in[4];
  const float* b_ih   = (const float*)d_in[5];
  const float* b_hh   = (const float*)d_in[6];
  const float* W1     = (const float*)d_in[7];
  const float* W2     = (const float*)d_in[8];
  const float* v      = (const float*)d_in[9];
  const float* Wp     = (const float*)d_in[10];
  const float* bp     = (const float*)d_in[11];
  const float* Wfc    = (const float*)d_in[12];
  const float* bfc    = (const float*)d_in[13];

  float* out     = (float*)d_out;
  float* logits  = out;                              // (B,T,V)
  float* hid_out = out + (size_t)B * T * V;          // (1,B,H)
  float* w_out   = hid_out + (size_t)B * H;          // (B,T,T)

  float* xp  = (float*)d_ws;
  float* rnn = xp  + (size_t)B * T * H;
  float* q   = rnn + (size_t)B * T * H;
  float* ky  = q   + (size_t)B * T * H;
  unsigned short* outb = (unsigned short*)(ky + (size_t)B * T * H);
  unsigned short* wfcb = outb + (size_t)B * T * H;

  prep_kernel<<<B * T + (V * H) / 1024, 128, 0, stream>>>(x, table, W_ih, b_ih, b_hh, Wfc, xp, wfcb);
  rnn_kernel<<<B, 256, 0, stream>>>(xp, hidden, W_hh, rnn, hid_out);
  qk_kernel<<<B * T, 256, 0, stream>>>(rnn, W1, W2, q, ky);
  attn_kernel<<<B * T, 256, 0, stream>>>(rnn, q, ky, v, Wp, bp, w_out, outb);
  gemm_kernel<<<V / 128, 256, 0, stream>>>(outb, wfcb, bfc, logits);
}